// Round 9
// baseline (386.399 us; speedup 1.0000x reference)
//
#include <hip/hip_runtime.h>
#include <hip/hip_bf16.h>

#define VOCAB 64
#define H 64
#define NB 128
#define SL 2048
#define NCH (SL / 4)

// ---------------- Kernel A: per-token tables ----------------
__global__ __launch_bounds__(64) void k_tables(
    const float* __restrict__ embed, const float* __restrict__ w1, const float* __restrict__ b1,
    const float* __restrict__ w2, const float* __restrict__ b2,
    const float* __restrict__ ln_g, const float* __restrict__ ln_b,
    const float* __restrict__ Wk, const float* __restrict__ Wv, const float* __restrict__ Wq,
    float* __restrict__ Ktab, float* __restrict__ Vtab, float* __restrict__ qtab)
{
  const int t = blockIdx.x;
  const int i = threadIdx.x;
  __shared__ float h0s[H];
  __shared__ float ff1s[2 * H];
  __shared__ float hs[H];

  h0s[i] = embed[t * H + i];
  __syncthreads();

  const float4* w1v = (const float4*)w1;
  float a0 = b1[i], a1 = b1[i + H];
#pragma unroll
  for (int j4 = 0; j4 < 16; ++j4) {
    const float4 hv = *(const float4*)&h0s[j4 * 4];
    const float4 wa = w1v[i * 16 + j4];
    const float4 wb = w1v[(i + H) * 16 + j4];
    a0 = fmaf(wa.x, hv.x, fmaf(wa.y, hv.y, fmaf(wa.z, hv.z, fmaf(wa.w, hv.w, a0))));
    a1 = fmaf(wb.x, hv.x, fmaf(wb.y, hv.y, fmaf(wb.z, hv.z, fmaf(wb.w, hv.w, a1))));
  }
  ff1s[i] = fmaxf(a0, 0.f);
  ff1s[i + H] = fmaxf(a1, 0.f);
  __syncthreads();

  const float4* w2v = (const float4*)w2;
  float z = h0s[i] + b2[i];
#pragma unroll
  for (int o4 = 0; o4 < 32; ++o4) {
    const float4 fv = *(const float4*)&ff1s[o4 * 4];
    const float4 wv = w2v[i * 32 + o4];
    z = fmaf(wv.x, fv.x, fmaf(wv.y, fv.y, fmaf(wv.z, fv.z, fmaf(wv.w, fv.w, z))));
  }

  float s = z;
#pragma unroll
  for (int m = 1; m < 64; m <<= 1) s += __shfl_xor(s, m);
  const float mu = s * (1.f / 64.f);
  const float d = z - mu;
  float s2 = d * d;
#pragma unroll
  for (int m = 1; m < 64; m <<= 1) s2 += __shfl_xor(s2, m);
  const float var = s2 * (1.f / 64.f);
  const float hv2 = d * rsqrtf(var + 1e-5f) * ln_g[i] + ln_b[i];
  hs[i] = hv2;
  __syncthreads();

  const float4* wkv = (const float4*)Wk;
  const float4* wvv = (const float4*)Wv;
  const float4* wqv = (const float4*)Wq;
  float kk = 0.f, vv = 0.f, qq = 0.f;
#pragma unroll
  for (int j4 = 0; j4 < 16; ++j4) {
    const float4 hj = *(const float4*)&hs[j4 * 4];
    const float4 ak = wkv[i * 16 + j4];
    const float4 av = wvv[i * 16 + j4];
    const float4 aq = wqv[i * 16 + j4];
    kk = fmaf(ak.x, hj.x, fmaf(ak.y, hj.y, fmaf(ak.z, hj.z, fmaf(ak.w, hj.w, kk))));
    vv = fmaf(av.x, hj.x, fmaf(av.y, hj.y, fmaf(av.z, hj.z, fmaf(av.w, hj.w, vv))));
    qq = fmaf(aq.x, hj.x, fmaf(aq.y, hj.y, fmaf(aq.z, hj.z, fmaf(aq.w, hj.w, qq))));
  }
  float n2 = kk * kk;
#pragma unroll
  for (int m = 1; m < 64; m <<= 1) n2 += __shfl_xor(n2, m);
  const float inv = 1.f / fmaxf(sqrtf(n2), 1e-12f);
  Ktab[t * H + i] = kk * inv;
  Vtab[t * H + i] = vv;
  qtab[t * H + i] = qq;
}

// ---------------- Kernel B: chunked P-cache delta-rule scan ----------------
// State per batch: M (64x64) and P = M . Ktab^T (64x64).
// Per 4-token chunk (a0..a3), exact serial math via:
//   q[j][t]  = P_pre[row j][a_t]           (bpermute, batched, latency-hidden)
//   g_st     = G[a_s][a_t]                 (bpermute from G rows)
//   tri-solve -> dl (4 sub + 6 fma / row)
//   P += sum_t dl_t (x) G[a_t,:]          (4 fma / row)
//   M += sum_t dl_t (x) K[a_t,:]          (DEFERRED one chunk: covers bperms)
__device__ __forceinline__ float bperm(int byteidx, float v) {
  return __int_as_float(__builtin_amdgcn_ds_bpermute(byteidx, __float_as_int(v)));
}

__global__ __launch_bounds__(512, 2) void k_scan(
    const int* __restrict__ x, const float* __restrict__ Ktab, const float* __restrict__ Vtab,
    float* __restrict__ Mout)
{
  const int bb = blockIdx.x >> 1;
  const int half = blockIdx.x & 1;
  const int tid = threadIdx.x;   // 0..511
  const int lane = tid & 63;
  const int wave = tid >> 6;     // 0..7
  const int r0 = wave * 4;       // local row base within this block's 32 rows

  __shared__ float smem[20560];
  float* Ks  = smem;             // [64][64]      4096
  float* KTs = smem + 4096;      // [64][65]      4160 (build scratch, padded)
  float* GKs = smem + 8256;      // [64][64][2]   8192  {G, K} interleaved
  float* Vs  = smem + 16448;     // [64][32]      2048  V[token][local_row]
  int*   xsh = (int*)(smem + 18496);  // 2048 + 16 ints

  // ---- stage K + K^T ----
#pragma unroll
  for (int u = 0; u < 2; ++u) {
    const int f4i = u * 512 + tid;  // 0..1023 over 64x64
    const float4 kv = ((const float4*)Ktab)[f4i];
    ((float4*)Ks)[f4i] = kv;
    const int row = f4i >> 4, c4 = (f4i & 15) * 4;
    KTs[(c4 + 0) * 65 + row] = kv.x;
    KTs[(c4 + 1) * 65 + row] = kv.y;
    KTs[(c4 + 2) * 65 + row] = kv.z;
    KTs[(c4 + 3) * 65 + row] = kv.w;
  }
  // ---- interleave K into GKs (.y slots) ----
#pragma unroll
  for (int u = 0; u < 8; ++u) {
    const int idx = u * 512 + tid;  // 0..4095
    GKs[idx * 2 + 1] = Ktab[idx];
  }
  // ---- stage V (this half's 32 rows) as [token][local_row] ----
  {
    const int t = tid >> 3, rq = (tid & 7) * 4;
    *(float4*)&Vs[t * 32 + rq] = *(const float4*)&Vtab[t * H + half * 32 + rq];
  }
  // ---- stage token row (+pad for prefetch over-run) ----
  {
    const int4* gx4 = (const int4*)(x + bb * SL);
    ((int4*)xsh)[tid] = gx4[tid];
    if (tid < 4) ((int4*)xsh)[512 + tid] = make_int4(0, 0, 0, 0);
  }
  __syncthreads();

  // ---- build Gram into GKs (.x slots): wave w computes rows [8w, 8w+8) ----
  {
    const int abase = wave * 8;
#pragma unroll 1
    for (int ar = 0; ar < 8; ++ar) {
      const int a = abase + ar;
      float acc = 0.f;
#pragma unroll
      for (int i = 0; i < H; i += 4) {
        const float4 ka = *(const float4*)&Ks[a * 64 + i];  // uniform broadcast
        acc = fmaf(ka.x, KTs[(i + 0) * 65 + lane], acc);
        acc = fmaf(ka.y, KTs[(i + 1) * 65 + lane], acc);
        acc = fmaf(ka.z, KTs[(i + 2) * 65 + lane], acc);
        acc = fmaf(ka.w, KTs[(i + 3) * 65 + lane], acc);
      }
      GKs[(a * 64 + lane) * 2] = acc;
    }
  }
  __syncthreads();

  const int lane2 = lane * 2;

  float P[4], Mr[4];
#pragma unroll
  for (int j = 0; j < 4; ++j) { P[j] = 0.f; Mr[j] = 0.f; }

  // chunk buffers (A/B) and deferred-M saves (bank 0/1)
  float GA[4], KA[4], GB[4], KB[4];
  float4 VA[4], VB[4];
  int biA[4], biB[4];
  float dl0[16], dl1[16], KS0[4], KS1[4];
#pragma unroll
  for (int i = 0; i < 16; ++i) dl1[i] = 0.f;
#pragma unroll
  for (int i = 0; i < 4; ++i) KS1[i] = 0.f;

#define PREF(G_, K_, V_, BI_, c_)                                          \
  {                                                                        \
    const int4 t_ = ((const int4*)xsh)[c_];                                \
    const int a0_ = t_.x, a1_ = t_.y, a2_ = t_.z, a3_ = t_.w;              \
    BI_[0] = a0_ << 2; BI_[1] = a1_ << 2; BI_[2] = a2_ << 2; BI_[3] = a3_ << 2; \
    const float2 gk0 = *(const float2*)&GKs[a0_ * 128 + lane2];            \
    const float2 gk1 = *(const float2*)&GKs[a1_ * 128 + lane2];            \
    const float2 gk2 = *(const float2*)&GKs[a2_ * 128 + lane2];            \
    const float2 gk3 = *(const float2*)&GKs[a3_ * 128 + lane2];            \
    G_[0] = gk0.x; K_[0] = gk0.y; G_[1] = gk1.x; K_[1] = gk1.y;            \
    G_[2] = gk2.x; K_[2] = gk2.y; G_[3] = gk3.x; K_[3] = gk3.y;            \
    V_[0] = *(const float4*)&Vs[a0_ * 32 + r0];                            \
    V_[1] = *(const float4*)&Vs[a1_ * 32 + r0];                            \
    V_[2] = *(const float4*)&Vs[a2_ * 32 + r0];                            \
    V_[3] = *(const float4*)&Vs[a3_ * 32 + r0];                            \
  }

#define BODY(G_, K_, V_, BI_, dlC_, dlP_, KSC_, KSP_, cn_)                 \
  {                                                                        \
    /* 1. batched extracts from frozen P and G (LDS pipe, latency-hidden) */ \
    const float q00 = bperm(BI_[0], P[0]), q01 = bperm(BI_[1], P[0]),      \
                q02 = bperm(BI_[2], P[0]), q03 = bperm(BI_[3], P[0]);      \
    const float q10 = bperm(BI_[0], P[1]), q11 = bperm(BI_[1], P[1]),      \
                q12 = bperm(BI_[2], P[1]), q13 = bperm(BI_[3], P[1]);      \
    const float q20 = bperm(BI_[0], P[2]), q21 = bperm(BI_[1], P[2]),      \
                q22 = bperm(BI_[2], P[2]), q23 = bperm(BI_[3], P[2]);      \
    const float q30 = bperm(BI_[0], P[3]), q31 = bperm(BI_[1], P[3]),      \
                q32 = bperm(BI_[2], P[3]), q33 = bperm(BI_[3], P[3]);      \
    const float g01 = bperm(BI_[1], G_[0]), g02 = bperm(BI_[2], G_[0]),    \
                g03 = bperm(BI_[3], G_[0]);                                \
    const float g12 = bperm(BI_[2], G_[1]), g13 = bperm(BI_[3], G_[1]);    \
    const float g23 = bperm(BI_[3], G_[2]);                                \
    /* 2. deferred M update for previous chunk (covers bperm latency) */   \
    Mr[0] = fmaf(dlP_[0],  KSP_[0], Mr[0]); Mr[0] = fmaf(dlP_[1],  KSP_[1], Mr[0]); \
    Mr[0] = fmaf(dlP_[2],  KSP_[2], Mr[0]); Mr[0] = fmaf(dlP_[3],  KSP_[3], Mr[0]); \
    Mr[1] = fmaf(dlP_[4],  KSP_[0], Mr[1]); Mr[1] = fmaf(dlP_[5],  KSP_[1], Mr[1]); \
    Mr[1] = fmaf(dlP_[6],  KSP_[2], Mr[1]); Mr[1] = fmaf(dlP_[7],  KSP_[3], Mr[1]); \
    Mr[2] = fmaf(dlP_[8],  KSP_[0], Mr[2]); Mr[2] = fmaf(dlP_[9],  KSP_[1], Mr[2]); \
    Mr[2] = fmaf(dlP_[10], KSP_[2], Mr[2]); Mr[2] = fmaf(dlP_[11], KSP_[3], Mr[2]); \
    Mr[3] = fmaf(dlP_[12], KSP_[0], Mr[3]); Mr[3] = fmaf(dlP_[13], KSP_[1], Mr[3]); \
    Mr[3] = fmaf(dlP_[14], KSP_[2], Mr[3]); Mr[3] = fmaf(dlP_[15], KSP_[3], Mr[3]); \
    /* 3. per-row 4x4 triangular solve (exact serial dl's) */              \
    dlC_[0]  = V_[0].x - q00;                                              \
    dlC_[1]  = fmaf(-dlC_[0], g01, V_[1].x - q01);                         \
    dlC_[2]  = fmaf(-dlC_[1], g12, fmaf(-dlC_[0], g02, V_[2].x - q02));    \
    dlC_[3]  = fmaf(-dlC_[2], g23, fmaf(-dlC_[1], g13, fmaf(-dlC_[0], g03, V_[3].x - q03))); \
    dlC_[4]  = V_[0].y - q10;                                              \
    dlC_[5]  = fmaf(-dlC_[4], g01, V_[1].y - q11);                         \
    dlC_[6]  = fmaf(-dlC_[5], g12, fmaf(-dlC_[4], g02, V_[2].y - q12));    \
    dlC_[7]  = fmaf(-dlC_[6], g23, fmaf(-dlC_[5], g13, fmaf(-dlC_[4], g03, V_[3].y - q13))); \
    dlC_[8]  = V_[0].z - q20;                                              \
    dlC_[9]  = fmaf(-dlC_[8], g01, V_[1].z - q21);                         \
    dlC_[10] = fmaf(-dlC_[9], g12, fmaf(-dlC_[8], g02, V_[2].z - q22));    \
    dlC_[11] = fmaf(-dlC_[10], g23, fmaf(-dlC_[9], g13, fmaf(-dlC_[8], g03, V_[3].z - q23))); \
    dlC_[12] = V_[0].w - q30;                                              \
    dlC_[13] = fmaf(-dlC_[12], g01, V_[1].w - q31);                        \
    dlC_[14] = fmaf(-dlC_[13], g12, fmaf(-dlC_[12], g02, V_[2].w - q32));  \
    dlC_[15] = fmaf(-dlC_[14], g23, fmaf(-dlC_[13], g13, fmaf(-dlC_[12], g03, V_[3].w - q33))); \
    /* 4. rank-4 P update */                                               \
    P[0] = fmaf(dlC_[3],  G_[3], fmaf(dlC_[2],  G_[2], fmaf(dlC_[1],  G_[1], fmaf(dlC_[0],  G_[0], P[0])))); \
    P[1] = fmaf(dlC_[7],  G_[3], fmaf(dlC_[6],  G_[2], fmaf(dlC_[5],  G_[1], fmaf(dlC_[4],  G_[0], P[1])))); \
    P[2] = fmaf(dlC_[11], G_[3], fmaf(dlC_[10], G_[2], fmaf(dlC_[9],  G_[1], fmaf(dlC_[8],  G_[0], P[2])))); \
    P[3] = fmaf(dlC_[15], G_[3], fmaf(dlC_[14], G_[2], fmaf(dlC_[13], G_[1], fmaf(dlC_[12], G_[0], P[3])))); \
    /* 5. save K for the deferred M; 6. prefetch chunk cn_ into this bank */ \
    KSC_[0] = K_[0]; KSC_[1] = K_[1]; KSC_[2] = K_[2]; KSC_[3] = K_[3];    \
    PREF(G_, K_, V_, BI_, cn_)                                             \
  }

  PREF(GA, KA, VA, biA, 0);
  PREF(GB, KB, VB, biB, 1);

#pragma unroll 1
  for (int n = 0; n < NCH / 2; ++n) {
    BODY(GA, KA, VA, biA, dl0, dl1, KS0, KS1, 2 * n + 2);  // chunk 2n
    BODY(GB, KB, VB, biB, dl1, dl0, KS1, KS0, 2 * n + 3);  // chunk 2n+1
  }
#undef BODY
#undef PREF

  // final deferred M (chunk NCH-1, bank 1)
#pragma unroll
  for (int j = 0; j < 4; ++j) {
    Mr[j] = fmaf(dl1[j * 4 + 0], KS1[0], Mr[j]);
    Mr[j] = fmaf(dl1[j * 4 + 1], KS1[1], Mr[j]);
    Mr[j] = fmaf(dl1[j * 4 + 2], KS1[2], Mr[j]);
    Mr[j] = fmaf(dl1[j * 4 + 3], KS1[3], Mr[j]);
  }

  // write M: row = half*32 + r0 + j, col = lane
  float* mp = Mout + ((size_t)bb * H + half * 32 + r0) * H + lane;
#pragma unroll
  for (int j = 0; j < 4; ++j) mp[j * H] = Mr[j];
}

// ---------------- Kernel C: attention + readout ----------------
__global__ __launch_bounds__(64) void k_final(
    const int* __restrict__ x, const float* __restrict__ Mws, const float* __restrict__ qtab,
    const float* __restrict__ Wout, const float* __restrict__ bout, float* __restrict__ out)
{
  const int b = blockIdx.x;
  const int i = threadIdx.x;
  __shared__ float Ml[H * 65];
  __shared__ float qs[H];
  __shared__ float attns[H];
  __shared__ float rcs[H];

  const float* Mg = Mws + (size_t)b * H * H;
#pragma unroll
  for (int j4 = 0; j4 < H; j4 += 4) {
    const float4 v = *(const float4*)(Mg + i * H + j4);
    Ml[i * 65 + j4 + 0] = v.x;
    Ml[i * 65 + j4 + 1] = v.y;
    Ml[i * 65 + j4 + 2] = v.z;
    Ml[i * 65 + j4 + 3] = v.w;
  }
  const int tok = x[b * SL + (SL - 1)];
  qs[i] = qtab[tok * H + i];
  __syncthreads();

  float acc = 0.f;
#pragma unroll
  for (int j = 0; j < H; ++j) acc = fmaf(Ml[j * 65 + i], qs[j], acc);
  const float sc = acc * 0.125f;

  float mx = sc;
#pragma unroll
  for (int m = 1; m < 64; m <<= 1) mx = fmaxf(mx, __shfl_xor(mx, m));
  const float e = expf(sc - mx);
  float ssum = e;
#pragma unroll
  for (int m = 1; m < 64; m <<= 1) ssum += __shfl_xor(ssum, m);
  attns[i] = e / ssum;
  __syncthreads();

  float cx = 0.f;
#pragma unroll
  for (int jj = 0; jj < H; ++jj) cx = fmaf(attns[jj], Ml[i * 65 + jj], cx);
  rcs[i] = fmaxf(cx, 0.f);
  __syncthreads();

  float o = bout[i];
#pragma unroll
  for (int j = 0; j < H; ++j) o = fmaf(Wout[i * H + j], rcs[j], o);
  out[b * VOCAB + i] = o;
}

extern "C" void kernel_launch(void* const* d_in, const int* in_sizes, int n_in,
                              void* d_out, int out_size, void* d_ws, size_t ws_size,
                              hipStream_t stream) {
  const int*   x     = (const int*)d_in[0];
  const float* embed = (const float*)d_in[1];
  const float* w1    = (const float*)d_in[2];
  const float* b1    = (const float*)d_in[3];
  const float* w2    = (const float*)d_in[4];
  const float* b2    = (const float*)d_in[5];
  const float* ln_g  = (const float*)d_in[6];
  const float* ln_b  = (const float*)d_in[7];
  const float* Wk    = (const float*)d_in[8];
  const float* Wv    = (const float*)d_in[9];
  const float* Wq    = (const float*)d_in[10];
  const float* Wout  = (const float*)d_in[11];
  const float* bout  = (const float*)d_in[12];

  float* ws   = (float*)d_ws;
  float* Ktab = ws;                 // 4096
  float* Vtab = ws + 4096;          // 4096
  float* qtab = ws + 8192;          // 4096
  float* Mws  = ws + 12288;         // 128*4096

  k_tables<<<dim3(VOCAB), dim3(H), 0, stream>>>(embed, w1, b1, w2, b2, ln_g, ln_b,
                                                Wk, Wv, Wq, Ktab, Vtab, qtab);
  k_scan<<<dim3(2 * NB), dim3(512), 0, stream>>>(x, Ktab, Vtab, Mws);
  k_final<<<dim3(NB), dim3(64), 0, stream>>>(x, Mws, qtab, Wout, bout, (float*)d_out);
}

// Round 10
// 212.770 us; speedup vs baseline: 1.8160x; 1.8160x over previous
//
#include <hip/hip_runtime.h>
#include <hip/hip_bf16.h>

#define VOCAB 64
#define H 64
#define NB 128
#define SL 2048

// ---------------- Kernel A: per-token tables ----------------
__global__ __launch_bounds__(64) void k_tables(
    const float* __restrict__ embed, const float* __restrict__ w1, const float* __restrict__ b1,
    const float* __restrict__ w2, const float* __restrict__ b2,
    const float* __restrict__ ln_g, const float* __restrict__ ln_b,
    const float* __restrict__ Wk, const float* __restrict__ Wv, const float* __restrict__ Wq,
    float* __restrict__ Ktab, float* __restrict__ Vtab, float* __restrict__ qtab)
{
  const int t = blockIdx.x;
  const int i = threadIdx.x;
  __shared__ float h0s[H];
  __shared__ float ff1s[2 * H];
  __shared__ float hs[H];

  h0s[i] = embed[t * H + i];
  __syncthreads();

  const float4* w1v = (const float4*)w1;
  float a0 = b1[i], a1 = b1[i + H];
#pragma unroll
  for (int j4 = 0; j4 < 16; ++j4) {
    const float4 hv = *(const float4*)&h0s[j4 * 4];
    const float4 wa = w1v[i * 16 + j4];
    const float4 wb = w1v[(i + H) * 16 + j4];
    a0 = fmaf(wa.x, hv.x, fmaf(wa.y, hv.y, fmaf(wa.z, hv.z, fmaf(wa.w, hv.w, a0))));
    a1 = fmaf(wb.x, hv.x, fmaf(wb.y, hv.y, fmaf(wb.z, hv.z, fmaf(wb.w, hv.w, a1))));
  }
  ff1s[i] = fmaxf(a0, 0.f);
  ff1s[i + H] = fmaxf(a1, 0.f);
  __syncthreads();

  const float4* w2v = (const float4*)w2;
  float z = h0s[i] + b2[i];
#pragma unroll
  for (int o4 = 0; o4 < 32; ++o4) {
    const float4 fv = *(const float4*)&ff1s[o4 * 4];
    const float4 wv = w2v[i * 32 + o4];
    z = fmaf(wv.x, fv.x, fmaf(wv.y, fv.y, fmaf(wv.z, fv.z, fmaf(wv.w, fv.w, z))));
  }

  float s = z;
#pragma unroll
  for (int m = 1; m < 64; m <<= 1) s += __shfl_xor(s, m);
  const float mu = s * (1.f / 64.f);
  const float d = z - mu;
  float s2 = d * d;
#pragma unroll
  for (int m = 1; m < 64; m <<= 1) s2 += __shfl_xor(s2, m);
  const float var = s2 * (1.f / 64.f);
  const float hv2 = d * rsqrtf(var + 1e-5f) * ln_g[i] + ln_b[i];
  hs[i] = hv2;
  __syncthreads();

  const float4* wkv = (const float4*)Wk;
  const float4* wvv = (const float4*)Wv;
  const float4* wqv = (const float4*)Wq;
  float kk = 0.f, vv = 0.f, qq = 0.f;
#pragma unroll
  for (int j4 = 0; j4 < 16; ++j4) {
    const float4 hj = *(const float4*)&hs[j4 * 4];
    const float4 ak = wkv[i * 16 + j4];
    const float4 av = wvv[i * 16 + j4];
    const float4 aq = wqv[i * 16 + j4];
    kk = fmaf(ak.x, hj.x, fmaf(ak.y, hj.y, fmaf(ak.z, hj.z, fmaf(ak.w, hj.w, kk))));
    vv = fmaf(av.x, hj.x, fmaf(av.y, hj.y, fmaf(av.z, hj.z, fmaf(av.w, hj.w, vv))));
    qq = fmaf(aq.x, hj.x, fmaf(aq.y, hj.y, fmaf(aq.z, hj.z, fmaf(aq.w, hj.w, qq))));
  }
  float n2 = kk * kk;
#pragma unroll
  for (int m = 1; m < 64; m <<= 1) n2 += __shfl_xor(n2, m);
  const float inv = 1.f / fmaxf(sqrtf(n2), 1e-12f);
  Ktab[t * H + i] = kk * inv;
  Vtab[t * H + i] = vv;
  qtab[t * H + i] = qq;
}

// ---------------- Kernel B: Q-cache delta-rule scan ----------------
// State per batch: M (64x64) and Q = M.Ktab^T - V^T (the V table is folded
// into the prediction cache at init). Step with token a:
//   dl_r  = -Q[r][a]                      (v_readlane; dl = v - pred exactly)
//   Q    += dl (x) G[a,:]                 (fma with -modifier, free negation)
//   M    += dl (x) K[a,:]
// lane = column; 8 waves x 4 rows; tokens via uniform s_load (no LDS staging).
__device__ __forceinline__ float rdl(float v, int sl) {
  return __int_as_float(__builtin_amdgcn_readlane(__float_as_int(v), sl));
}

__global__ __launch_bounds__(512) void k_scan(
    const int* __restrict__ x, const float* __restrict__ Ktab, const float* __restrict__ Vtab,
    float* __restrict__ Mout)
{
  const int bb = blockIdx.x >> 1;
  const int half = blockIdx.x & 1;
  const int tid = threadIdx.x;   // 0..511
  const int lane = tid & 63;
  const int wave = tid >> 6;     // 0..7
  const int r0 = wave * 4;       // local row base within this block's 32 rows

  __shared__ float smem[16448];
  float* Ks  = smem;             // [64][64]      4096
  float* KTs = smem + 4096;      // [64][65]      4160 (Gram-build scratch)
  float* GKs = smem + 8256;      // [64][64][2]   8192  {G, K} interleaved

  // ---- stage K + K^T ----
#pragma unroll
  for (int u = 0; u < 2; ++u) {
    const int f4i = u * 512 + tid;  // 0..1023 over 64x64
    const float4 kv = ((const float4*)Ktab)[f4i];
    ((float4*)Ks)[f4i] = kv;
    const int row = f4i >> 4, c4 = (f4i & 15) * 4;
    KTs[(c4 + 0) * 65 + row] = kv.x;
    KTs[(c4 + 1) * 65 + row] = kv.y;
    KTs[(c4 + 2) * 65 + row] = kv.z;
    KTs[(c4 + 3) * 65 + row] = kv.w;
  }
  // ---- interleave K into GKs (.y slots) ----
#pragma unroll
  for (int u = 0; u < 8; ++u) {
    const int idx = u * 512 + tid;  // 0..4095
    GKs[idx * 2 + 1] = Ktab[idx];
  }
  __syncthreads();

  // ---- build Gram into GKs (.x slots): wave w computes rows [8w, 8w+8) ----
  {
    const int abase = wave * 8;
#pragma unroll 1
    for (int ar = 0; ar < 8; ++ar) {
      const int a = abase + ar;
      float acc = 0.f;
#pragma unroll
      for (int i = 0; i < H; i += 4) {
        const float4 ka = *(const float4*)&Ks[a * 64 + i];  // uniform broadcast
        acc = fmaf(ka.x, KTs[(i + 0) * 65 + lane], acc);
        acc = fmaf(ka.y, KTs[(i + 1) * 65 + lane], acc);
        acc = fmaf(ka.z, KTs[(i + 2) * 65 + lane], acc);
        acc = fmaf(ka.w, KTs[(i + 3) * 65 + lane], acc);
      }
      GKs[(a * 64 + lane) * 2] = acc;
    }
  }
  __syncthreads();

  // ---- init Q = -V^T slice (P=0), M = 0 ----
  float Q[4], Mr[4];
#pragma unroll
  for (int j = 0; j < 4; ++j) {
    Q[j] = -Vtab[lane * H + half * 32 + r0 + j];
    Mr[j] = 0.f;
  }

  const int* __restrict__ xp = x + bb * SL;  // block-uniform -> scalar loads
  const int lane2 = lane * 2;

  float gA, kA, gB, kB, gC, kC, gD, kD;

#define PREF(G_, K_, a_)                                                   \
  {                                                                        \
    const float2 gk = *(const float2*)&GKs[(a_) * 128 + lane2];            \
    G_ = gk.x; K_ = gk.y;                                                  \
  }

#define STEP(G_, K_, a_)                                                   \
  {                                                                        \
    const float q0 = rdl(Q[0], a_);                                        \
    const float q1 = rdl(Q[1], a_);                                        \
    const float q2 = rdl(Q[2], a_);                                        \
    const float q3 = rdl(Q[3], a_);                                        \
    Q[0] = fmaf(-q0, G_, Q[0]);  Mr[0] = fmaf(-q0, K_, Mr[0]);             \
    Q[1] = fmaf(-q1, G_, Q[1]);  Mr[1] = fmaf(-q1, K_, Mr[1]);             \
    Q[2] = fmaf(-q2, G_, Q[2]);  Mr[2] = fmaf(-q2, K_, Mr[2]);             \
    Q[3] = fmaf(-q3, G_, Q[3]);  Mr[3] = fmaf(-q3, K_, Mr[3]);             \
  }

  int4 tg = *(const int4*)(xp);   // uniform address -> s_load_dwordx4
  PREF(gA, kA, tg.x);
  PREF(gB, kB, tg.y);

#pragma unroll 1
  for (int n = 0; n < SL / 4; ++n) {
    const int offn = (n + 1 < SL / 4) ? (n + 1) * 4 : 0;  // uniform, in-bounds
    const int4 tgN = *(const int4*)(xp + offn);
    PREF(gC, kC, tg.z);
    STEP(gA, kA, tg.x);
    PREF(gD, kD, tg.w);
    STEP(gB, kB, tg.y);
    PREF(gA, kA, tgN.x);
    STEP(gC, kC, tg.z);
    PREF(gB, kB, tgN.y);
    STEP(gD, kD, tg.w);
    tg = tgN;
  }
#undef PREF
#undef STEP

  // write M: row = half*32 + r0 + j, col = lane
  float* mp = Mout + ((size_t)bb * H + half * 32 + r0) * H + lane;
#pragma unroll
  for (int j = 0; j < 4; ++j) mp[j * H] = Mr[j];
}

// ---------------- Kernel C: attention + readout ----------------
__global__ __launch_bounds__(64) void k_final(
    const int* __restrict__ x, const float* __restrict__ Mws, const float* __restrict__ qtab,
    const float* __restrict__ Wout, const float* __restrict__ bout, float* __restrict__ out)
{
  const int b = blockIdx.x;
  const int i = threadIdx.x;
  __shared__ float Ml[H * 65];
  __shared__ float qs[H];
  __shared__ float attns[H];
  __shared__ float rcs[H];

  const float* Mg = Mws + (size_t)b * H * H;
#pragma unroll
  for (int j4 = 0; j4 < H; j4 += 4) {
    const float4 v = *(const float4*)(Mg + i * H + j4);
    Ml[i * 65 + j4 + 0] = v.x;
    Ml[i * 65 + j4 + 1] = v.y;
    Ml[i * 65 + j4 + 2] = v.z;
    Ml[i * 65 + j4 + 3] = v.w;
  }
  const int tok = x[b * SL + (SL - 1)];
  qs[i] = qtab[tok * H + i];
  __syncthreads();

  float acc = 0.f;
#pragma unroll
  for (int j = 0; j < H; ++j) acc = fmaf(Ml[j * 65 + i], qs[j], acc);
  const float sc = acc * 0.125f;

  float mx = sc;
#pragma unroll
  for (int m = 1; m < 64; m <<= 1) mx = fmaxf(mx, __shfl_xor(mx, m));
  const float e = expf(sc - mx);
  float ssum = e;
#pragma unroll
  for (int m = 1; m < 64; m <<= 1) ssum += __shfl_xor(ssum, m);
  attns[i] = e / ssum;
  __syncthreads();

  float cx = 0.f;
#pragma unroll
  for (int jj = 0; jj < H; ++jj) cx = fmaf(attns[jj], Ml[i * 65 + jj], cx);
  rcs[i] = fmaxf(cx, 0.f);
  __syncthreads();

  float o = bout[i];
#pragma unroll
  for (int j = 0; j < H; ++j) o = fmaf(Wout[i * H + j], rcs[j], o);
  out[b * VOCAB + i] = o;
}

extern "C" void kernel_launch(void* const* d_in, const int* in_sizes, int n_in,
                              void* d_out, int out_size, void* d_ws, size_t ws_size,
                              hipStream_t stream) {
  const int*   x     = (const int*)d_in[0];
  const float* embed = (const float*)d_in[1];
  const float* w1    = (const float*)d_in[2];
  const float* b1    = (const float*)d_in[3];
  const float* w2    = (const float*)d_in[4];
  const float* b2    = (const float*)d_in[5];
  const float* ln_g  = (const float*)d_in[6];
  const float* ln_b  = (const float*)d_in[7];
  const float* Wk    = (const float*)d_in[8];
  const float* Wv    = (const float*)d_in[9];
  const float* Wq    = (const float*)d_in[10];
  const float* Wout  = (const float*)d_in[11];
  const float* bout  = (const float*)d_in[12];

  float* ws   = (float*)d_ws;
  float* Ktab = ws;                 // 4096
  float* Vtab = ws + 4096;          // 4096
  float* qtab = ws + 8192;          // 4096
  float* Mws  = ws + 12288;         // 128*4096

  k_tables<<<dim3(VOCAB), dim3(H), 0, stream>>>(embed, w1, b1, w2, b2, ln_g, ln_b,
                                                Wk, Wv, Wq, Ktab, Vtab, qtab);
  k_scan<<<dim3(2 * NB), dim3(512), 0, stream>>>(x, Ktab, Vtab, Mws);
  k_final<<<dim3(NB), dim3(64), 0, stream>>>(x, Mws, qtab, Wout, bout, (float*)d_out);
}